// Round 4
// baseline (4125.471 us; speedup 1.0000x reference)
//
#include <hip/hip_runtime.h>

// HiPPO-LegS scan — round 4: f16-split (Markidis) MFMA everywhere.
// s_t = A_t s_{t-1} + bv_t ⊗ x_t;  all A_t (and products) lower-triangular.
// Decomposition: 256 chunks of 4 timesteps, 16 groups of 16 chunks.
//  k1  (512 blk): chunk units (M,w) via 3 products, col-split x2.
//  k2  ( 80 blk): within-group inclusive prefix scan (15 products), 5 col-slices.
//  k2b (  1 blk): group entry states E[g] via 15 matvec steps over group totals.
//  k3  (256 blk): per chunk: entry = pre o E[g], then 4 replay matvecs + out.
// fp32 value = hi(f16) + lo(f16); product via 3 MFMAs (hh, hl, lh).
// B-operand lives transposed+split in LDS; A-operand streamed from global with
// ALL loads for a step batched up front (latency paid once per step).

#define LDK 136      // f16 k-stride of transposed LDS operands (2-way-conflict free)
#define UNIT 20480   // floats per unit: 128*128 M + 128*32 w
#define WOFF 16384

using f16 = _Float16;
using f16x8 = __attribute__((ext_vector_type(8))) f16;
using f16x4 = __attribute__((ext_vector_type(4))) f16;
using f32x4 = __attribute__((ext_vector_type(4))) float;

__device__ __forceinline__ void split8(const float* v, f16x8& hi, f16x8& lo) {
#pragma unroll
  for (int j = 0; j < 8; ++j) {
    const float x = v[j];
    const f16 h = (f16)x;
    hi[j] = h;
    lo[j] = (f16)(x - (float)h);
  }
}

__device__ __forceinline__ f32x4 mfma3(f16x8 ah, f16x8 al, f16x8 bh, f16x8 bl, f32x4 c) {
  c = __builtin_amdgcn_mfma_f32_16x16x32_f16(ah, bh, c, 0, 0, 0);
  c = __builtin_amdgcn_mfma_f32_16x16x32_f16(ah, bl, c, 0, 0, 0);
  c = __builtin_amdgcn_mfma_f32_16x16x32_f16(al, bh, c, 0, 0, 0);
  return c;
}

// ---------------------------------------------------------------------------
// One chain step: D = Mg (128x128 f32 row-major, lower-tri, upper zero-filled)
// times P, where P (128 x [cols CT0*16 .. (CT0+NCT)*16)) lives transposed+split
// in LDS: Pt{h,l}[n_local*LDK + k]. ct>=8 are state (w) columns.
// Wave w owns row-tiles {w, 7-w}. Tile skips: D-tile (rt,ct<8) needs ct<=rt,
// k-tiles kt in [ct>>1, rt>>1]; state tiles kt in [0, rt>>1].
// WMODE 0: write Pt only; state tiles += bv⊗x.
// WMODE 1: write global oM/oW only; state tiles += bv⊗x.
// WMODE 2: write Pt AND global; state tiles += wadd (global f32 [128][32]).
template <int CT0, int NCT, int WMODE>
__device__ __forceinline__ void prod_step(const float* __restrict__ Mg,
                                          f16* __restrict__ Pth, f16* __restrict__ Ptl,
                                          const float* __restrict__ wadd,
                                          const float* __restrict__ bv,
                                          const float* __restrict__ xr,
                                          float* __restrict__ oM,
                                          float* __restrict__ oW) {
  constexpr bool HAS_STATE = (CT0 + NCT > 8);
  constexpr int KT0 = HAS_STATE ? 0 : (CT0 >> 1);
  const int tid = threadIdx.x;
  const int w = tid >> 6, l = tid & 63;
  const int lr = l & 15, q = l >> 4;
  const int rts[2] = {w, 7 - w};
  // ---- batched A-frag loads (all issued before any use) ----
  float rawA[2][4][8];
  bool act[2];
#pragma unroll
  for (int p = 0; p < 2; ++p) {
    const int rt = rts[p];
    act[p] = HAS_STATE || (rt >= CT0);
    if (!act[p]) continue;
    const float* base = Mg + (size_t)(rt * 16 + lr) * 128 + q * 8;
    const int ktmax = rt >> 1;
#pragma unroll
    for (int kt = 0; kt < 4; ++kt) {
      if (kt >= KT0 && kt <= ktmax) {
        *(float4*)&rawA[p][kt][0] = *(const float4*)(base + kt * 32);
        *(float4*)&rawA[p][kt][4] = *(const float4*)(base + kt * 32 + 4);
      }
    }
  }
  // ---- convert to f16 hi/lo frags ----
  f16x8 Ah[2][4], Al[2][4];
#pragma unroll
  for (int p = 0; p < 2; ++p) {
    if (!act[p]) continue;
    const int ktmax = rts[p] >> 1;
#pragma unroll
    for (int kt = 0; kt < 4; ++kt)
      if (kt >= KT0 && kt <= ktmax) split8(rawA[p][kt], Ah[p][kt], Al[p][kt]);
  }
  // ---- MFMA ----
  f32x4 acc[2][NCT];
#pragma unroll
  for (int p = 0; p < 2; ++p)
#pragma unroll
    for (int t = 0; t < NCT; ++t) acc[p][t] = (f32x4){0.f, 0.f, 0.f, 0.f};
#pragma unroll
  for (int p = 0; p < 2; ++p) {
    if (!act[p]) continue;
    const int rt = rts[p];
    const int ktmax = rt >> 1;
#pragma unroll
    for (int t = 0; t < NCT; ++t) {
      const int ct = CT0 + t;
      if (ct < 8 && ct > rt) continue;
      const int kt0 = (ct < 8) ? (ct >> 1) : 0;
      f32x4 a = acc[p][t];
      for (int kt = kt0; kt <= ktmax; ++kt) {
        const int off = (t * 16 + lr) * LDK + kt * 32 + q * 8;
        a = mfma3(Ah[p][kt], Al[p][kt], *(const f16x8*)(Pth + off),
                  *(const f16x8*)(Ptl + off), a);
      }
      acc[p][t] = a;
    }
  }
  __syncthreads();  // all Pt reads complete before in-place writes
  // ---- epilogue ----
#pragma unroll
  for (int p = 0; p < 2; ++p) {
    if (!act[p]) continue;
    const int rt = rts[p];
    const int m0 = rt * 16 + q * 4;
#pragma unroll
    for (int t = 0; t < NCT; ++t) {
      const int ct = CT0 + t;
      if (ct < 8 && ct > rt) continue;
      float v[4];
      if (ct >= 8) {
        const int b = (ct - 8) * 16 + lr;
        if (WMODE == 2) {
#pragma unroll
          for (int r = 0; r < 4; ++r) v[r] = acc[p][t][r] + wadd[(m0 + r) * 32 + b];
        } else {
          const float xb = xr[b];
#pragma unroll
          for (int r = 0; r < 4; ++r) v[r] = acc[p][t][r] + bv[m0 + r] * xb;
        }
        if (WMODE >= 1) {
#pragma unroll
          for (int r = 0; r < 4; ++r) oW[(m0 + r) * 32 + b] = v[r];
        }
      } else {
#pragma unroll
        for (int r = 0; r < 4; ++r) v[r] = acc[p][t][r];
        if (WMODE >= 1) {
#pragma unroll
          for (int r = 0; r < 4; ++r) oM[(m0 + r) * 128 + ct * 16 + lr] = v[r];
        }
      }
      if (WMODE != 1) {
        f16x4 h4, l4;
#pragma unroll
        for (int r = 0; r < 4; ++r) {
          const f16 h = (f16)v[r];
          h4[r] = h;
          l4[r] = (f16)(v[r] - (float)h);
        }
        *(f16x4*)(Pth + (t * 16 + lr) * LDK + m0) = h4;
        *(f16x4*)(Ptl + (t * 16 + lr) * LDK + m0) = l4;
      }
    }
  }
  // zero-fill strictly-upper tiles of global M in this slice's matrix cols
  if (WMODE >= 1 && CT0 < 8) {
    constexpr int C4LO = CT0 * 16;
    constexpr int CEND = (CT0 + NCT > 8) ? 8 : (CT0 + NCT);
    constexpr int C4N = (CEND * 16 - C4LO) >> 2;
    for (int f = tid; f < 128 * C4N; f += 256) {
      const int i = f / C4N;
      const int j4 = C4LO + (f - i * C4N) * 4;
      if ((j4 >> 4) > (i >> 4))
        *(float4*)(oM + i * 128 + j4) = make_float4(0.f, 0.f, 0.f, 0.f);
    }
  }
  if (WMODE != 1) __syncthreads();  // Pt writes visible before next step
}

// ---------------------------------------------------------------------------
// Matvec chain step: D (128x32) = Mg * S; S transposed+split in LDS St[b][k].
// WM 1: D += wadd (f32 [128][32]);  WM 2: D += bv⊗x.
// Optional: write D as f32 to outp (layout [b*128+n]) and/or as f16 pair to Eh/El.
template <int WM>
__device__ __forceinline__ void matvec_step(const float* __restrict__ Mg,
                                            const float* __restrict__ wadd,
                                            const float* __restrict__ bv,
                                            const float* __restrict__ xr,
                                            f16* __restrict__ Sth, f16* __restrict__ Stl,
                                            float* __restrict__ outp,
                                            f16* __restrict__ Eh, f16* __restrict__ El) {
  const int tid = threadIdx.x;
  const int w = tid >> 6, l = tid & 63;
  const int lr = l & 15, q = l >> 4;
  const int rts[2] = {w, 7 - w};
  float rawA[2][4][8];
#pragma unroll
  for (int p = 0; p < 2; ++p) {
    const int rt = rts[p];
    const float* base = Mg + (size_t)(rt * 16 + lr) * 128 + q * 8;
#pragma unroll
    for (int kt = 0; kt < 4; ++kt)
      if (kt <= (rt >> 1)) {
        *(float4*)&rawA[p][kt][0] = *(const float4*)(base + kt * 32);
        *(float4*)&rawA[p][kt][4] = *(const float4*)(base + kt * 32 + 4);
      }
  }
  f16x8 Ah[2][4], Al[2][4];
#pragma unroll
  for (int p = 0; p < 2; ++p)
#pragma unroll
    for (int kt = 0; kt < 4; ++kt)
      if (kt <= (rts[p] >> 1)) split8(rawA[p][kt], Ah[p][kt], Al[p][kt]);
  f32x4 acc[2][2];
#pragma unroll
  for (int p = 0; p < 2; ++p) {
    acc[p][0] = (f32x4){0.f, 0.f, 0.f, 0.f};
    acc[p][1] = (f32x4){0.f, 0.f, 0.f, 0.f};
  }
#pragma unroll
  for (int p = 0; p < 2; ++p) {
    const int rt = rts[p];
#pragma unroll
    for (int t = 0; t < 2; ++t) {
      f32x4 a = acc[p][t];
      for (int kt = 0; kt <= (rt >> 1); ++kt) {
        const int off = (t * 16 + lr) * LDK + kt * 32 + q * 8;
        a = mfma3(Ah[p][kt], Al[p][kt], *(const f16x8*)(Sth + off),
                  *(const f16x8*)(Stl + off), a);
      }
      acc[p][t] = a;
    }
  }
  __syncthreads();
#pragma unroll
  for (int p = 0; p < 2; ++p) {
    const int rt = rts[p];
    const int m0 = rt * 16 + q * 4;
#pragma unroll
    for (int t = 0; t < 2; ++t) {
      const int b = t * 16 + lr;
      float v[4];
      if (WM == 1) {
#pragma unroll
        for (int r = 0; r < 4; ++r) v[r] = acc[p][t][r] + wadd[(m0 + r) * 32 + b];
      } else {
        const float xb = xr[b];
#pragma unroll
        for (int r = 0; r < 4; ++r) v[r] = acc[p][t][r] + bv[m0 + r] * xb;
      }
      f16x4 h4, l4;
#pragma unroll
      for (int r = 0; r < 4; ++r) {
        const f16 h = (f16)v[r];
        h4[r] = h;
        l4[r] = (f16)(v[r] - (float)h);
      }
      *(f16x4*)(Sth + b * LDK + m0) = h4;
      *(f16x4*)(Stl + b * LDK + m0) = l4;
      if (outp) *(float4*)(outp + b * 128 + m0) = make_float4(v[0], v[1], v[2], v[3]);
      if (Eh) {
        *(f16x4*)(Eh + b * 128 + m0) = h4;
        *(f16x4*)(El + b * 128 + m0) = l4;
      }
    }
  }
  __syncthreads();
}

// ---------------------------------------------------------------------------
// K1: chunk units. grid 512: c = bid&255, slice = bid>>8 (cols 0..79 / 80..159).
__global__ __launch_bounds__(256) void k1_chunks(const float* __restrict__ A,
                                                 const float* __restrict__ x,
                                                 const float* __restrict__ Bv,
                                                 float* __restrict__ U) {
  __shared__ __align__(16) f16 Pth[80 * LDK];
  __shared__ __align__(16) f16 Ptl[80 * LDK];
  const int tid = threadIdx.x;
  const int c = blockIdx.x & 255;
  const int sl = blockIdx.x >> 8;
  const int l0 = 4 * c;
  const float* A0 = A + (size_t)l0 * 16384;
  if (sl == 0) {
    for (int f = tid; f < 128 * 20; f += 256) {
      const int k = f / 20;
      const int j4 = (f - k * 20) * 4;
      const float4 v = *(const float4*)(A0 + k * 128 + j4);
      const float vv[4] = {v.x, v.y, v.z, v.w};
#pragma unroll
      for (int e = 0; e < 4; ++e) {
        const int n = j4 + e;
        const f16 h = (f16)vv[e];
        Pth[n * LDK + k] = h;
        Ptl[n * LDK + k] = (f16)(vv[e] - (float)h);
      }
    }
  } else {
    for (int f = tid; f < 128 * 12; f += 256) {
      const int k = f / 12;
      const int j4 = 80 + (f - k * 12) * 4;
      const float4 v = *(const float4*)(A0 + k * 128 + j4);
      const float vv[4] = {v.x, v.y, v.z, v.w};
#pragma unroll
      for (int e = 0; e < 4; ++e) {
        const int n = j4 + e - 80;
        const f16 h = (f16)vv[e];
        Pth[n * LDK + k] = h;
        Ptl[n * LDK + k] = (f16)(vv[e] - (float)h);
      }
    }
    for (int f = tid; f < 32 * 128; f += 256) {
      const int b = f >> 7, k = f & 127;
      const float u = Bv[(size_t)l0 * 128 + k] * x[(size_t)l0 * 32 + b];
      const f16 h = (f16)u;
      Pth[(48 + b) * LDK + k] = h;
      Ptl[(48 + b) * LDK + k] = (f16)(u - (float)h);
    }
  }
  __syncthreads();
  float* oM = U + (size_t)c * UNIT;
  if (sl == 0) {
    prod_step<0, 5, 0>(A + (size_t)(l0 + 1) * 16384, Pth, Ptl, nullptr, nullptr, nullptr, nullptr, nullptr);
    prod_step<0, 5, 0>(A + (size_t)(l0 + 2) * 16384, Pth, Ptl, nullptr, nullptr, nullptr, nullptr, nullptr);
    prod_step<0, 5, 1>(A + (size_t)(l0 + 3) * 16384, Pth, Ptl, nullptr, nullptr, nullptr, oM, nullptr);
  } else {
    prod_step<5, 5, 0>(A + (size_t)(l0 + 1) * 16384, Pth, Ptl, nullptr,
                       Bv + (size_t)(l0 + 1) * 128, x + (size_t)(l0 + 1) * 32, nullptr, nullptr);
    prod_step<5, 5, 0>(A + (size_t)(l0 + 2) * 16384, Pth, Ptl, nullptr,
                       Bv + (size_t)(l0 + 2) * 128, x + (size_t)(l0 + 2) * 32, nullptr, nullptr);
    prod_step<5, 5, 1>(A + (size_t)(l0 + 3) * 16384, Pth, Ptl, nullptr,
                       Bv + (size_t)(l0 + 3) * 128, x + (size_t)(l0 + 3) * 32, oM, oM + WOFF);
  }
}

// ---------------------------------------------------------------------------
// K2: within-group inclusive prefix scan. grid 80: g = bid/5, slice s = bid%5.
// pre[g][j] (j=1..15) stored at PRE + (g*15 + j-1)*UNIT (unit format).
__global__ __launch_bounds__(256) void k2_scan(const float* __restrict__ U,
                                               float* __restrict__ PRE) {
  __shared__ __align__(16) f16 Pth[32 * LDK];
  __shared__ __align__(16) f16 Ptl[32 * LDK];
  const int tid = threadIdx.x;
  const int g = blockIdx.x / 5, s = blockIdx.x % 5;
  const float* u0 = U + (size_t)(16 * g) * UNIT;
  if (s < 4) {
    for (int f = tid; f < 128 * 8; f += 256) {
      const int k = f >> 3, j4 = 32 * s + (f & 7) * 4;
      const float4 v = *(const float4*)(u0 + k * 128 + j4);
      const float vv[4] = {v.x, v.y, v.z, v.w};
#pragma unroll
      for (int e = 0; e < 4; ++e) {
        const int n = j4 + e - 32 * s;
        const f16 h = (f16)vv[e];
        Pth[n * LDK + k] = h;
        Ptl[n * LDK + k] = (f16)(vv[e] - (float)h);
      }
    }
  } else {
    for (int f = tid; f < 128 * 8; f += 256) {
      const int k = f >> 3, b4 = (f & 7) * 4;
      const float4 v = *(const float4*)(u0 + WOFF + k * 32 + b4);
      const float vv[4] = {v.x, v.y, v.z, v.w};
#pragma unroll
      for (int e = 0; e < 4; ++e) {
        const int n = b4 + e;
        const f16 h = (f16)vv[e];
        Pth[n * LDK + k] = h;
        Ptl[n * LDK + k] = (f16)(vv[e] - (float)h);
      }
    }
  }
  __syncthreads();
  for (int j = 1; j <= 15; ++j) {
    const float* Mg = U + (size_t)(16 * g + j) * UNIT;
    float* o = PRE + (size_t)(g * 15 + j - 1) * UNIT;
    switch (s) {
      case 0: prod_step<0, 2, 2>(Mg, Pth, Ptl, Mg + WOFF, nullptr, nullptr, o, o + WOFF); break;
      case 1: prod_step<2, 2, 2>(Mg, Pth, Ptl, Mg + WOFF, nullptr, nullptr, o, o + WOFF); break;
      case 2: prod_step<4, 2, 2>(Mg, Pth, Ptl, Mg + WOFF, nullptr, nullptr, o, o + WOFF); break;
      case 3: prod_step<6, 2, 2>(Mg, Pth, Ptl, Mg + WOFF, nullptr, nullptr, o, o + WOFF); break;
      default: prod_step<8, 2, 2>(Mg, Pth, Ptl, Mg + WOFF, nullptr, nullptr, o, o + WOFF); break;
    }
  }
}

// ---------------------------------------------------------------------------
// K2b: group entry states E[g] (f16 hi/lo, layout [g][b][k]); E[0]=0.
__global__ __launch_bounds__(256) void k2b_groups(const float* __restrict__ PRE,
                                                  f16* __restrict__ Eh,
                                                  f16* __restrict__ El) {
  __shared__ __align__(16) f16 Sth[32 * LDK];
  __shared__ __align__(16) f16 Stl[32 * LDK];
  const int tid = threadIdx.x;
  for (int f = tid; f < 32 * LDK; f += 256) { Sth[f] = (f16)0.f; Stl[f] = (f16)0.f; }
  for (int f = tid; f < 4096; f += 256) { Eh[f] = (f16)0.f; El[f] = (f16)0.f; }
  __syncthreads();
  for (int g = 1; g < 16; ++g) {
    const float* Mg = PRE + (size_t)((g - 1) * 15 + 14) * UNIT;  // pre[g-1][15]
    matvec_step<1>(Mg, Mg + WOFF, nullptr, nullptr, Sth, Stl, nullptr,
                   Eh + (size_t)g * 4096, El + (size_t)g * 4096);
  }
}

// ---------------------------------------------------------------------------
// K3: replay. chunk c: St = E[g]; if j>0 apply pre[g][j-1]; then 4 steps + out.
__global__ __launch_bounds__(256) void k3_replay(const float* __restrict__ A,
                                                 const float* __restrict__ x,
                                                 const float* __restrict__ Bv,
                                                 const float* __restrict__ U,
                                                 const float* __restrict__ PRE,
                                                 const f16* __restrict__ Eh,
                                                 const f16* __restrict__ El,
                                                 float* __restrict__ out) {
  __shared__ __align__(16) f16 Sth[32 * LDK];
  __shared__ __align__(16) f16 Stl[32 * LDK];
  const int tid = threadIdx.x;
  const int c = blockIdx.x, g = c >> 4, j = c & 15;
  for (int f = tid; f < 512; f += 256) {
    const int b = f >> 4, k0 = (f & 15) * 8;
    *(f16x8*)(Sth + b * LDK + k0) = *(const f16x8*)(Eh + (size_t)g * 4096 + b * 128 + k0);
    *(f16x8*)(Stl + b * LDK + k0) = *(const f16x8*)(El + (size_t)g * 4096 + b * 128 + k0);
  }
  __syncthreads();
  if (j > 0) {
    const float* Mg = (j == 1) ? (U + (size_t)(16 * g) * UNIT)
                               : (PRE + (size_t)(g * 15 + j - 2) * UNIT);
    matvec_step<1>(Mg, Mg + WOFF, nullptr, nullptr, Sth, Stl, nullptr, nullptr, nullptr);
  }
  for (int t = 0; t < 4; ++t) {
    const int lt = 4 * c + t;
    matvec_step<2>(A + (size_t)lt * 16384, nullptr, Bv + (size_t)lt * 128,
                   x + (size_t)lt * 32, Sth, Stl, out + (size_t)lt * 4096, nullptr, nullptr);
  }
}

// ---------------------------------------------------------------------------
extern "C" void kernel_launch(void* const* d_in, const int* in_sizes, int n_in,
                              void* d_out, int out_size, void* d_ws, size_t ws_size,
                              hipStream_t stream) {
  const float* x  = (const float*)d_in[0];  // (1024, 32)
  const float* A  = (const float*)d_in[1];  // (1024, 128, 128) lower-triangular
  const float* Bv = (const float*)d_in[2];  // (1024, 128)
  float* out = (float*)d_out;               // (1024, 32, 128)
  float* U = (float*)d_ws;                  // 256 units = 20 MB
  float* PRE = U + 256ull * UNIT;           // 240 prefix units = 19.7 MB
  f16* Eh = (f16*)(PRE + 240ull * UNIT);    // 16x4096 f16
  f16* El = Eh + 16 * 4096;

  k1_chunks<<<512, 256, 0, stream>>>(A, x, Bv, U);
  k2_scan<<<80, 256, 0, stream>>>(U, PRE);
  k2b_groups<<<1, 256, 0, stream>>>(PRE, Eh, El);
  k3_replay<<<256, 256, 0, stream>>>(A, x, Bv, U, PRE, Eh, El, out);
}

// Round 5
// 373.236 us; speedup vs baseline: 11.0532x; 11.0532x over previous
//
#include <hip/hip_runtime.h>

// HiPPO-LegS scan — round 5: "flipped" f16-split MFMA scan, plain layouts only.
// All chain states are carried TRANSPOSED (s^T, P^T) so every stored matrix is
// consumed as the MFMA B-operand directly from row-major ("plain") memory:
//   B-frag of M^T  ==  contiguous rows of plain M.   A-operand = state in LDS.
// Pipeline:
//  k1 (512 blk): chunk units M_c = A_{4c+3}..A_{4c}, w_c  (3 products, row-split x2)
//  k2_gops (32 blk): group ops G_g = prod of 16 chunk Ms (15-step chain)
//  k2_entries (16 blk): entry states E[c] for all 256 chunks (redundant group
//      prefix <=15 matvec steps + within-group 15 matvec steps)
//  k3 (256 blk): per chunk: s^T = E[c]; 4 replay matvecs + coalesced out writes.
// fp32 = hi(f16)+lo(f16); product via 3 MFMAs. Lower-triangular tile skips.
// Workspace ~25.3 MB.

#define LDK 136  // f16 k-stride of LDS state rows (272B rows, 16B aligned)

using f16 = _Float16;
typedef __attribute__((ext_vector_type(8))) f16 f16x8;
typedef __attribute__((ext_vector_type(4))) float f32x4;

__device__ __forceinline__ f32x4 mfma3(f16x8 ah, f16x8 al, f16x8 bh, f16x8 bl,
                                       f32x4 c) {
  c = __builtin_amdgcn_mfma_f32_16x16x32_f16(ah, bh, c, 0, 0, 0);
  c = __builtin_amdgcn_mfma_f32_16x16x32_f16(ah, bl, c, 0, 0, 0);
  c = __builtin_amdgcn_mfma_f32_16x16x32_f16(al, bh, c, 0, 0, 0);
  return c;
}

__device__ __forceinline__ void split8(const float* v, f16x8& h, f16x8& l) {
#pragma unroll
  for (int j = 0; j < 8; ++j) {
    const float x = v[j];
    const f16 hh = (f16)x;
    h[j] = hh;
    l[j] = (f16)(x - (float)hh);
  }
}

// global m-tile owned by (h, slot): h=0 -> {0,7,1,6}, h=1 -> {2,5,3,4}
__device__ __forceinline__ int slot2mt(int h, int slot) {
  if (h == 0) return (slot & 1) ? 7 - (slot >> 1) : (slot >> 1);
  return (slot & 1) ? 5 - (slot >> 1) : 2 + (slot >> 1);
}

// ---------------------------------------------------------------------------
// chain_step: P' (LDS, rows = this block's 5 m-tiles: 4 matrix + 1 w) updates
// P' <- P' * B^T where B is 128x128 lower-tri read from global (f32 or f16 pair).
// wave wv (0..4) owns m-tile `mt` (local rows wv*16..+15). 2 barriers.
// EXTRA==1: w-rows += bv (x) outer (aux0=x+l*32, aux1=Bv+l*128)
// EXTRA==2: w-rows += w_add f32 [n][32b] (aux0)
template <bool F32B, int EXTRA>
__device__ __forceinline__ void chain_step(const float* __restrict__ Bf,
                                           const f16* __restrict__ Bh16,
                                           const f16* __restrict__ Bl16,
                                           const float* __restrict__ aux0,
                                           const float* __restrict__ aux1,
                                           f16* __restrict__ Ph,
                                           f16* __restrict__ Pl,
                                           int wv, int mt) {
  const int lane = threadIdx.x & 63;
  const int lr = lane & 15, q = lane >> 4;
  const bool wrow = (mt >= 8);
  const int ktA0 = wrow ? 0 : (mt >> 1);
  // A-operand: this wave's P' rows (loaded before mid-barrier)
  f16x8 ah[4], al[4];
#pragma unroll
  for (int kt = 0; kt < 4; ++kt) {
    if (kt >= ktA0) {
      const int off = (wv * 16 + lr) * LDK + kt * 32 + q * 8;
      ah[kt] = *(const f16x8*)(Ph + off);
      al[kt] = *(const f16x8*)(Pl + off);
    }
  }
  f32x4 acc[8];
#pragma unroll
  for (int nt = 0; nt < 8; ++nt) acc[nt] = (f32x4){0.f, 0.f, 0.f, 0.f};

  float raw[2][4][8];   // F32B ping-pong (raw-level pipelining)
  f16x8 b16h[2][4], b16l[2][4];
  f16x8 ch[4], cl[4];   // F32B converted slot

  auto loadB = [&](int nt, int s) {
#pragma unroll
    for (int kt = 0; kt < 4; ++kt) {
      if (kt >= ktA0 && kt <= (nt >> 1)) {
        if (F32B) {
          const float* p = Bf + (nt * 16 + lr) * 128 + kt * 32 + q * 8;
          *(float4*)&raw[s][kt][0] = *(const float4*)p;
          *(float4*)&raw[s][kt][4] = *(const float4*)(p + 4);
        } else {
          const int o = (nt * 16 + lr) * 128 + kt * 32 + q * 8;
          b16h[s][kt] = *(const f16x8*)(Bh16 + o);
          b16l[s][kt] = *(const f16x8*)(Bl16 + o);
        }
      }
    }
  };

  if (wrow || mt == 0) loadB(0, 0);
#pragma unroll
  for (int nt = 0; nt < 8; ++nt) {
    const int cur = nt & 1;
    if (nt < 7 && (wrow || (nt + 1) >= mt)) loadB(nt + 1, cur ^ 1);
    if (wrow || nt >= mt) {
      if (F32B) {
#pragma unroll
        for (int kt = 0; kt < 4; ++kt)
          if (kt >= ktA0 && kt <= (nt >> 1)) split8(raw[cur][kt], ch[kt], cl[kt]);
#pragma unroll
        for (int kt = 0; kt < 4; ++kt)
          if (kt >= ktA0 && kt <= (nt >> 1))
            acc[nt] = mfma3(ah[kt], al[kt], ch[kt], cl[kt], acc[nt]);
      } else {
#pragma unroll
        for (int kt = 0; kt < 4; ++kt)
          if (kt >= ktA0 && kt <= (nt >> 1))
            acc[nt] = mfma3(ah[kt], al[kt], b16h[cur][kt], b16l[cur][kt], acc[nt]);
      }
    }
  }
  __syncthreads();  // all waves done reading P' before in-place writes
#pragma unroll
  for (int nt = 0; nt < 8; ++nt) {
    if (!(wrow || nt >= mt)) continue;
    float v[4] = {acc[nt][0], acc[nt][1], acc[nt][2], acc[nt][3]};
    if (wrow) {
      const int b0 = (mt - 8) * 16 + q * 4;  // global batch index base
      if (EXTRA == 2) {
        const float4 w4 = *(const float4*)(aux0 + (nt * 16 + lr) * 32 + b0);
        v[0] += w4.x; v[1] += w4.y; v[2] += w4.z; v[3] += w4.w;
      } else if (EXTRA == 1) {
        const float4 x4 = *(const float4*)(aux0 + b0);
        const float bn = aux1[nt * 16 + lr];
        v[0] += bn * x4.x; v[1] += bn * x4.y; v[2] += bn * x4.z; v[3] += bn * x4.w;
      }
    }
#pragma unroll
    for (int r = 0; r < 4; ++r) {
      const int o = (wv * 16 + q * 4 + r) * LDK + nt * 16 + lr;
      const f16 hh = (f16)v[r];
      Ph[o] = hh;
      Pl[o] = (f16)(v[r] - (float)hh);
    }
  }
  __syncthreads();
}

// copy P' (= result^T in LDS) out as PLAIN M (f16 hi/lo) + w (f32 [n][32])
__device__ __forceinline__ void chain_copyout(const f16* __restrict__ Ph,
                                              const f16* __restrict__ Pl, int h,
                                              f16* __restrict__ oMh,
                                              f16* __restrict__ oMl,
                                              float* __restrict__ oW) {
  const int tid = threadIdx.x;
  for (int t = tid; t < 1024; t += 320) {  // (i 0..127, slot 0..3, half 0..1)
    const int i = t >> 3;
    const int slot = (t >> 1) & 3;
    const int half = t & 1;
    const int mtg = slot2mt(h, slot);
    f16x8 hv, lv;
#pragma unroll
    for (int e = 0; e < 8; ++e) {
      hv[e] = Ph[(slot * 16 + half * 8 + e) * LDK + i];
      lv[e] = Pl[(slot * 16 + half * 8 + e) * LDK + i];
    }
    *(f16x8*)(oMh + i * 128 + mtg * 16 + half * 8) = hv;
    *(f16x8*)(oMl + i * 128 + mtg * 16 + half * 8) = lv;
  }
  for (int t = tid; t < 512; t += 320) {  // (n 0..127, b4 0..3)
    const int n = t >> 2, b4 = (t & 3) * 4;
    float4 o;
    float* po = (float*)&o;
#pragma unroll
    for (int e = 0; e < 4; ++e)
      po[e] = (float)Ph[(64 + b4 + e) * LDK + n] + (float)Pl[(64 + b4 + e) * LDK + n];
    *(float4*)(oW + n * 32 + h * 16 + b4) = o;
  }
}

// ---------------------------------------------------------------------------
// state_step: s^T (LDS 32xLDK f16 hi/lo) <- s^T * B^T (+ adds). 256 threads.
// wave wv owns nt in {wv, 7-wv}, both batch tiles. Optional f32 out write.
template <bool F32B, int EXTRA>
__device__ __forceinline__ void state_step(const float* __restrict__ Bf,
                                           const f16* __restrict__ Bh16,
                                           const f16* __restrict__ Bl16,
                                           const float* __restrict__ aux0,
                                           const float* __restrict__ aux1,
                                           f16* __restrict__ Sh,
                                           f16* __restrict__ Sl,
                                           float* __restrict__ outp) {
  const int tid = threadIdx.x;
  const int wv = tid >> 6;
  const int lane = tid & 63, lr = lane & 15, q = lane >> 4;
  const int nts[2] = {wv, 7 - wv};
  const int ktAmax = (7 - wv) >> 1;
  f16x8 ah[2][4], al[2][4];
#pragma unroll
  for (int bt = 0; bt < 2; ++bt)
#pragma unroll
    for (int kt = 0; kt < 4; ++kt)
      if (kt <= ktAmax) {
        const int off = (bt * 16 + lr) * LDK + kt * 32 + q * 8;
        ah[bt][kt] = *(const f16x8*)(Sh + off);
        al[bt][kt] = *(const f16x8*)(Sl + off);
      }
  // B-frags: both nt's, batched loads up front
  f16x8 bh[2][4], bl[2][4];
  if (F32B) {
    float raw[2][4][8];
#pragma unroll
    for (int ni = 0; ni < 2; ++ni) {
      const int nt = nts[ni];
#pragma unroll
      for (int kt = 0; kt < 4; ++kt)
        if (kt <= (nt >> 1)) {
          const float* p = Bf + (nt * 16 + lr) * 128 + kt * 32 + q * 8;
          *(float4*)&raw[ni][kt][0] = *(const float4*)p;
          *(float4*)&raw[ni][kt][4] = *(const float4*)(p + 4);
        }
    }
#pragma unroll
    for (int ni = 0; ni < 2; ++ni) {
      const int nt = nts[ni];
#pragma unroll
      for (int kt = 0; kt < 4; ++kt)
        if (kt <= (nt >> 1)) split8(raw[ni][kt], bh[ni][kt], bl[ni][kt]);
    }
  } else {
#pragma unroll
    for (int ni = 0; ni < 2; ++ni) {
      const int nt = nts[ni];
#pragma unroll
      for (int kt = 0; kt < 4; ++kt)
        if (kt <= (nt >> 1)) {
          const int o = (nt * 16 + lr) * 128 + kt * 32 + q * 8;
          bh[ni][kt] = *(const f16x8*)(Bh16 + o);
          bl[ni][kt] = *(const f16x8*)(Bl16 + o);
        }
    }
  }
  f32x4 acc[2][2];
#pragma unroll
  for (int bt = 0; bt < 2; ++bt)
#pragma unroll
    for (int ni = 0; ni < 2; ++ni) acc[bt][ni] = (f32x4){0.f, 0.f, 0.f, 0.f};
#pragma unroll
  for (int ni = 0; ni < 2; ++ni) {
    const int nt = nts[ni];
#pragma unroll
    for (int kt = 0; kt < 4; ++kt)
      if (kt <= (nt >> 1)) {
        acc[0][ni] = mfma3(ah[0][kt], al[0][kt], bh[ni][kt], bl[ni][kt], acc[0][ni]);
        acc[1][ni] = mfma3(ah[1][kt], al[1][kt], bh[ni][kt], bl[ni][kt], acc[1][ni]);
      }
  }
  __syncthreads();
#pragma unroll
  for (int bt = 0; bt < 2; ++bt)
#pragma unroll
    for (int ni = 0; ni < 2; ++ni) {
      const int nt = nts[ni];
      float v[4] = {acc[bt][ni][0], acc[bt][ni][1], acc[bt][ni][2], acc[bt][ni][3]};
      const int b0 = bt * 16 + q * 4;
      if (EXTRA == 2) {
        const float4 w4 = *(const float4*)(aux0 + (nt * 16 + lr) * 32 + b0);
        v[0] += w4.x; v[1] += w4.y; v[2] += w4.z; v[3] += w4.w;
      } else if (EXTRA == 1) {
        const float4 x4 = *(const float4*)(aux0 + b0);
        const float bn = aux1[nt * 16 + lr];
        v[0] += bn * x4.x; v[1] += bn * x4.y; v[2] += bn * x4.z; v[3] += bn * x4.w;
      }
      if (outp) {
#pragma unroll
        for (int r = 0; r < 4; ++r) outp[(b0 + r) * 128 + nt * 16 + lr] = v[r];
      }
#pragma unroll
      for (int r = 0; r < 4; ++r) {
        const int o = (b0 + r) * LDK + nt * 16 + lr;
        const f16 hh = (f16)v[r];
        Sh[o] = hh;
        Sl[o] = (f16)(v[r] - (float)hh);
      }
    }
  __syncthreads();
}

// ---------------------------------------------------------------------------
// K1: chunk units. grid 512 (c = bid>>1, h = bid&1), 320 threads.
__global__ __launch_bounds__(320) void k1_chunks(const float* __restrict__ A,
                                                 const float* __restrict__ x,
                                                 const float* __restrict__ Bv,
                                                 f16* __restrict__ Mh,
                                                 f16* __restrict__ Ml,
                                                 float* __restrict__ Wf) {
  __shared__ f16 Ph[80 * LDK], Pl[80 * LDK];
  const int tid = threadIdx.x;
  const int c = blockIdx.x >> 1, h = blockIdx.x & 1;
  const int l0 = 4 * c;
  const float* A0 = A + (size_t)l0 * 16384;
  // init matrix rows: P'[m][k] = A0[k][m] for our 64 m-cols
  for (int t = tid; t < 2048; t += 320) {
    const int k = t >> 4, u = t & 15;
    const int slot = u >> 2, fo = (u & 3) * 4;
    const int mtg = slot2mt(h, slot);
    const float4 v = *(const float4*)(A0 + k * 128 + mtg * 16 + fo);
    const float vv[4] = {v.x, v.y, v.z, v.w};
#pragma unroll
    for (int e = 0; e < 4; ++e) {
      const f16 hh = (f16)vv[e];
      Ph[(slot * 16 + fo + e) * LDK + k] = hh;
      Pl[(slot * 16 + fo + e) * LDK + k] = (f16)(vv[e] - (float)hh);
    }
  }
  // init w rows: u0^T[b][n] = x[l0][b]*Bv[l0][n]
  for (int t = tid; t < 512; t += 320) {
    const int b = t >> 5, n4 = (t & 31) * 4;
    const float xb = x[l0 * 32 + h * 16 + b];
#pragma unroll
    for (int e = 0; e < 4; ++e) {
      const float u = xb * Bv[l0 * 128 + n4 + e];
      const f16 hh = (f16)u;
      Ph[(64 + b) * LDK + n4 + e] = hh;
      Pl[(64 + b) * LDK + n4 + e] = (f16)(u - (float)hh);
    }
  }
  __syncthreads();
  const int wv = tid >> 6;
  const int mt = (wv == 4) ? (8 + h) : slot2mt(h, wv);
#pragma unroll 1
  for (int j = 1; j <= 3; ++j) {
    const int l = l0 + j;
    chain_step<true, 1>(A + (size_t)l * 16384, nullptr, nullptr, x + l * 32,
                        Bv + l * 128, Ph, Pl, wv, mt);
  }
  chain_copyout(Ph, Pl, h, Mh + (size_t)c * 16384, Ml + (size_t)c * 16384,
                Wf + (size_t)c * 4096);
}

// ---------------------------------------------------------------------------
// K2a: group operators G_g (15-step chain over chunk units). grid 32, 320 thr.
__global__ __launch_bounds__(320) void k2_gops(const f16* __restrict__ Mh,
                                               const f16* __restrict__ Ml,
                                               const float* __restrict__ Wf,
                                               f16* __restrict__ Gmh,
                                               f16* __restrict__ Gml,
                                               float* __restrict__ Gw) {
  __shared__ f16 Ph[80 * LDK], Pl[80 * LDK];
  const int tid = threadIdx.x;
  const int g = blockIdx.x >> 1, h = blockIdx.x & 1;
  const int c0 = 16 * g;
  // init: P' = M_{c0}^T | w_{c0}^T
  for (int t = tid; t < 1024; t += 320) {
    const int k = t >> 3, u = t & 7;
    const int slot = u >> 1, half = u & 1;
    const int mtg = slot2mt(h, slot);
    const f16x8 hv = *(const f16x8*)(Mh + (size_t)c0 * 16384 + k * 128 + mtg * 16 + half * 8);
    const f16x8 lv = *(const f16x8*)(Ml + (size_t)c0 * 16384 + k * 128 + mtg * 16 + half * 8);
#pragma unroll
    for (int e = 0; e < 8; ++e) {
      Ph[(slot * 16 + half * 8 + e) * LDK + k] = hv[e];
      Pl[(slot * 16 + half * 8 + e) * LDK + k] = lv[e];
    }
  }
  for (int t = tid; t < 2048; t += 320) {
    const int n = t >> 4, b = t & 15;
    const float wv0 = Wf[(size_t)c0 * 4096 + n * 32 + h * 16 + b];
    const f16 hh = (f16)wv0;
    Ph[(64 + b) * LDK + n] = hh;
    Pl[(64 + b) * LDK + n] = (f16)(wv0 - (float)hh);
  }
  __syncthreads();
  const int wv = tid >> 6;
  const int mt = (wv == 4) ? (8 + h) : slot2mt(h, wv);
#pragma unroll 1
  for (int j = 1; j <= 15; ++j) {
    const int cc = c0 + j;
    chain_step<false, 2>(nullptr, Mh + (size_t)cc * 16384, Ml + (size_t)cc * 16384,
                         Wf + (size_t)cc * 4096, nullptr, Ph, Pl, wv, mt);
  }
  chain_copyout(Ph, Pl, h, Gmh + (size_t)g * 16384, Gml + (size_t)g * 16384,
                Gw + (size_t)g * 4096);
}

// ---------------------------------------------------------------------------
// K2b: entry states for all 256 chunks. grid 16, 256 thr.
__global__ __launch_bounds__(256) void k2_entries(const f16* __restrict__ Mh,
                                                  const f16* __restrict__ Ml,
                                                  const float* __restrict__ Wf,
                                                  const f16* __restrict__ Gmh,
                                                  const f16* __restrict__ Gml,
                                                  const float* __restrict__ Gw,
                                                  f16* __restrict__ Eh,
                                                  f16* __restrict__ El) {
  __shared__ f16 Sh[32 * LDK], Sl[32 * LDK];
  const int tid = threadIdx.x;
  const int g = blockIdx.x;
  for (int t = tid; t < 32 * LDK; t += 256) { Sh[t] = (f16)0.f; Sl[t] = (f16)0.f; }
  __syncthreads();
#pragma unroll 1
  for (int hh = 0; hh < g; ++hh)
    state_step<false, 2>(nullptr, Gmh + (size_t)hh * 16384, Gml + (size_t)hh * 16384,
                         Gw + (size_t)hh * 4096, nullptr, Sh, Sl, nullptr);
#pragma unroll 1
  for (int j = 0; j < 16; ++j) {
    const int cc = 16 * g + j;
    for (int t = tid; t < 512; t += 256) {
      const int b = t >> 4, k8 = (t & 15) * 8;
      *(f16x8*)(Eh + (size_t)cc * 4096 + b * 128 + k8) = *(const f16x8*)(Sh + b * LDK + k8);
      *(f16x8*)(El + (size_t)cc * 4096 + b * 128 + k8) = *(const f16x8*)(Sl + b * LDK + k8);
    }
    if (j < 15)
      state_step<false, 2>(nullptr, Mh + (size_t)cc * 16384, Ml + (size_t)cc * 16384,
                           Wf + (size_t)cc * 4096, nullptr, Sh, Sl, nullptr);
  }
}

// ---------------------------------------------------------------------------
// K3: replay. grid 256, 256 thr.
__global__ __launch_bounds__(256) void k3_replay(const float* __restrict__ A,
                                                 const float* __restrict__ x,
                                                 const float* __restrict__ Bv,
                                                 const f16* __restrict__ Eh,
                                                 const f16* __restrict__ El,
                                                 float* __restrict__ out) {
  __shared__ f16 Sh[32 * LDK], Sl[32 * LDK];
  const int tid = threadIdx.x;
  const int c = blockIdx.x;
  for (int t = tid; t < 512; t += 256) {
    const int b = t >> 4, k8 = (t & 15) * 8;
    *(f16x8*)(Sh + b * LDK + k8) = *(const f16x8*)(Eh + (size_t)c * 4096 + b * 128 + k8);
    *(f16x8*)(Sl + b * LDK + k8) = *(const f16x8*)(El + (size_t)c * 4096 + b * 128 + k8);
  }
  __syncthreads();
#pragma unroll 1
  for (int t4 = 0; t4 < 4; ++t4) {
    const int l = 4 * c + t4;
    state_step<true, 1>(A + (size_t)l * 16384, nullptr, nullptr, x + l * 32,
                        Bv + l * 128, Sh, Sl, out + (size_t)l * 4096);
  }
}

// ---------------------------------------------------------------------------
extern "C" void kernel_launch(void* const* d_in, const int* in_sizes, int n_in,
                              void* d_out, int out_size, void* d_ws, size_t ws_size,
                              hipStream_t stream) {
  const float* x  = (const float*)d_in[0];  // (1024, 32)
  const float* A  = (const float*)d_in[1];  // (1024, 128, 128) lower-triangular
  const float* Bv = (const float*)d_in[2];  // (1024, 128)
  float* out = (float*)d_out;               // (1024, 32, 128)

  f16* Mh = (f16*)d_ws;                     // 256*16384 f16
  f16* Ml = Mh + 256 * 16384;
  float* Wf = (float*)(Ml + 256 * 16384);   // 256*4096 f32
  f16* Gmh = (f16*)(Wf + 256 * 4096);       // 16*16384
  f16* Gml = Gmh + 16 * 16384;
  float* Gw = (float*)(Gml + 16 * 16384);   // 16*4096 f32
  f16* Eh = (f16*)(Gw + 16 * 4096);         // 256*4096
  f16* El = Eh + 256 * 4096;                // total ~25.3 MB

  k1_chunks<<<512, 320, 0, stream>>>(A, x, Bv, Mh, Ml, Wf);
  k2_gops<<<32, 320, 0, stream>>>(Mh, Ml, Wf, Gmh, Gml, Gw);
  k2_entries<<<16, 256, 0, stream>>>(Mh, Ml, Wf, Gmh, Gml, Gw, Eh, El);
  k3_replay<<<256, 256, 0, stream>>>(A, x, Bv, Eh, El, out);
}

// Round 6
// 339.686 us; speedup vs baseline: 12.1449x; 1.0988x over previous
//
#include <hip/hip_runtime.h>

// HiPPO-LegS scan — round 6: round-5 flipped f16-split MFMA engine, but the
// serial scan middle (k2_gops 15-deep / k2_entries 30-deep) is replaced by a
// WIDE Kogge-Stone within-group prefix scan (4 levels x 512 blocks, depth 1
// product per block) + a 16-block group-entry matvec kernel.
// Pipeline: k1 (512) -> ks<1,2,4,8> (512 each, ping-pong buffers) -> kgroup(16)
// -> k3 (256: entry + prefix-apply + 4 replay matvecs + out).
// Workspace ~42.2 MB.

#define LDK 136  // f16 k-stride of LDS state rows

using f16 = _Float16;
typedef __attribute__((ext_vector_type(8))) f16 f16x8;
typedef __attribute__((ext_vector_type(4))) float f32x4;

__device__ __forceinline__ f32x4 mfma3(f16x8 ah, f16x8 al, f16x8 bh, f16x8 bl,
                                       f32x4 c) {
  c = __builtin_amdgcn_mfma_f32_16x16x32_f16(ah, bh, c, 0, 0, 0);
  c = __builtin_amdgcn_mfma_f32_16x16x32_f16(ah, bl, c, 0, 0, 0);
  c = __builtin_amdgcn_mfma_f32_16x16x32_f16(al, bh, c, 0, 0, 0);
  return c;
}

__device__ __forceinline__ void split8(const float* v, f16x8& h, f16x8& l) {
#pragma unroll
  for (int j = 0; j < 8; ++j) {
    const float x = v[j];
    const f16 hh = (f16)x;
    h[j] = hh;
    l[j] = (f16)(x - (float)hh);
  }
}

// global m-tile owned by (h, slot): h=0 -> {0,7,1,6}, h=1 -> {2,5,3,4}
__device__ __forceinline__ int slot2mt(int h, int slot) {
  if (h == 0) return (slot & 1) ? 7 - (slot >> 1) : (slot >> 1);
  return (slot & 1) ? 5 - (slot >> 1) : 2 + (slot >> 1);
}

// ---------------------------------------------------------------------------
// chain_step: P' (LDS, rows = this block's 5 m-tiles: 4 matrix + 1 w) updates
// P' <- P' * B^T where B is 128x128 lower-tri read from global (f32 or f16 pair).
// wave wv (0..4) owns m-tile `mt` (local rows wv*16..+15). 2 barriers.
// EXTRA==1: w-rows += bv (x) outer (aux0=x+l*32, aux1=Bv+l*128)
// EXTRA==2: w-rows += w_add f32 [n][32b] (aux0)
template <bool F32B, int EXTRA>
__device__ __forceinline__ void chain_step(const float* __restrict__ Bf,
                                           const f16* __restrict__ Bh16,
                                           const f16* __restrict__ Bl16,
                                           const float* __restrict__ aux0,
                                           const float* __restrict__ aux1,
                                           f16* __restrict__ Ph,
                                           f16* __restrict__ Pl,
                                           int wv, int mt) {
  const int lane = threadIdx.x & 63;
  const int lr = lane & 15, q = lane >> 4;
  const bool wrow = (mt >= 8);
  const int ktA0 = wrow ? 0 : (mt >> 1);
  f16x8 ah[4], al[4];
#pragma unroll
  for (int kt = 0; kt < 4; ++kt) {
    if (kt >= ktA0) {
      const int off = (wv * 16 + lr) * LDK + kt * 32 + q * 8;
      ah[kt] = *(const f16x8*)(Ph + off);
      al[kt] = *(const f16x8*)(Pl + off);
    }
  }
  f32x4 acc[8];
#pragma unroll
  for (int nt = 0; nt < 8; ++nt) acc[nt] = (f32x4){0.f, 0.f, 0.f, 0.f};

  float raw[2][4][8];
  f16x8 b16h[2][4], b16l[2][4];
  f16x8 ch[4], cl[4];

  auto loadB = [&](int nt, int s) {
#pragma unroll
    for (int kt = 0; kt < 4; ++kt) {
      if (kt >= ktA0 && kt <= (nt >> 1)) {
        if (F32B) {
          const float* p = Bf + (nt * 16 + lr) * 128 + kt * 32 + q * 8;
          *(float4*)&raw[s][kt][0] = *(const float4*)p;
          *(float4*)&raw[s][kt][4] = *(const float4*)(p + 4);
        } else {
          const int o = (nt * 16 + lr) * 128 + kt * 32 + q * 8;
          b16h[s][kt] = *(const f16x8*)(Bh16 + o);
          b16l[s][kt] = *(const f16x8*)(Bl16 + o);
        }
      }
    }
  };

  if (wrow || mt == 0) loadB(0, 0);
#pragma unroll
  for (int nt = 0; nt < 8; ++nt) {
    const int cur = nt & 1;
    if (nt < 7 && (wrow || (nt + 1) >= mt)) loadB(nt + 1, cur ^ 1);
    if (wrow || nt >= mt) {
      if (F32B) {
#pragma unroll
        for (int kt = 0; kt < 4; ++kt)
          if (kt >= ktA0 && kt <= (nt >> 1)) split8(raw[cur][kt], ch[kt], cl[kt]);
#pragma unroll
        for (int kt = 0; kt < 4; ++kt)
          if (kt >= ktA0 && kt <= (nt >> 1))
            acc[nt] = mfma3(ah[kt], al[kt], ch[kt], cl[kt], acc[nt]);
      } else {
#pragma unroll
        for (int kt = 0; kt < 4; ++kt)
          if (kt >= ktA0 && kt <= (nt >> 1))
            acc[nt] = mfma3(ah[kt], al[kt], b16h[cur][kt], b16l[cur][kt], acc[nt]);
      }
    }
  }
  __syncthreads();
#pragma unroll
  for (int nt = 0; nt < 8; ++nt) {
    if (!(wrow || nt >= mt)) continue;
    float v[4] = {acc[nt][0], acc[nt][1], acc[nt][2], acc[nt][3]};
    if (wrow) {
      const int b0 = (mt - 8) * 16 + q * 4;
      if (EXTRA == 2) {
        const float4 w4 = *(const float4*)(aux0 + (nt * 16 + lr) * 32 + b0);
        v[0] += w4.x; v[1] += w4.y; v[2] += w4.z; v[3] += w4.w;
      } else if (EXTRA == 1) {
        const float4 x4 = *(const float4*)(aux0 + b0);
        const float bn = aux1[nt * 16 + lr];
        v[0] += bn * x4.x; v[1] += bn * x4.y; v[2] += bn * x4.z; v[3] += bn * x4.w;
      }
    }
#pragma unroll
    for (int r = 0; r < 4; ++r) {
      const int o = (wv * 16 + q * 4 + r) * LDK + nt * 16 + lr;
      const f16 hh = (f16)v[r];
      Ph[o] = hh;
      Pl[o] = (f16)(v[r] - (float)hh);
    }
  }
  __syncthreads();
}

// copy P' (= result^T in LDS) out as PLAIN M (f16 hi/lo) + w (f32 [n][32])
__device__ __forceinline__ void chain_copyout(const f16* __restrict__ Ph,
                                              const f16* __restrict__ Pl, int h,
                                              f16* __restrict__ oMh,
                                              f16* __restrict__ oMl,
                                              float* __restrict__ oW) {
  const int tid = threadIdx.x;
  for (int t = tid; t < 1024; t += 320) {
    const int i = t >> 3;
    const int slot = (t >> 1) & 3;
    const int half = t & 1;
    const int mtg = slot2mt(h, slot);
    f16x8 hv, lv;
#pragma unroll
    for (int e = 0; e < 8; ++e) {
      hv[e] = Ph[(slot * 16 + half * 8 + e) * LDK + i];
      lv[e] = Pl[(slot * 16 + half * 8 + e) * LDK + i];
    }
    *(f16x8*)(oMh + i * 128 + mtg * 16 + half * 8) = hv;
    *(f16x8*)(oMl + i * 128 + mtg * 16 + half * 8) = lv;
  }
  for (int t = tid; t < 512; t += 320) {
    const int n = t >> 2, b4 = (t & 3) * 4;
    float4 o;
    float* po = (float*)&o;
#pragma unroll
    for (int e = 0; e < 4; ++e)
      po[e] = (float)Ph[(64 + b4 + e) * LDK + n] + (float)Pl[(64 + b4 + e) * LDK + n];
    *(float4*)(oW + n * 32 + h * 16 + b4) = o;
  }
}

// ---------------------------------------------------------------------------
// state_step: s^T (LDS 32xLDK f16 hi/lo) <- s^T * B^T (+ adds). 256 threads.
template <bool F32B, int EXTRA>
__device__ __forceinline__ void state_step(const float* __restrict__ Bf,
                                           const f16* __restrict__ Bh16,
                                           const f16* __restrict__ Bl16,
                                           const float* __restrict__ aux0,
                                           const float* __restrict__ aux1,
                                           f16* __restrict__ Sh,
                                           f16* __restrict__ Sl,
                                           float* __restrict__ outp) {
  const int tid = threadIdx.x;
  const int wv = tid >> 6;
  const int lane = tid & 63, lr = lane & 15, q = lane >> 4;
  const int nts[2] = {wv, 7 - wv};
  const int ktAmax = (7 - wv) >> 1;
  f16x8 ah[2][4], al[2][4];
#pragma unroll
  for (int bt = 0; bt < 2; ++bt)
#pragma unroll
    for (int kt = 0; kt < 4; ++kt)
      if (kt <= ktAmax) {
        const int off = (bt * 16 + lr) * LDK + kt * 32 + q * 8;
        ah[bt][kt] = *(const f16x8*)(Sh + off);
        al[bt][kt] = *(const f16x8*)(Sl + off);
      }
  f16x8 bh[2][4], bl[2][4];
  if (F32B) {
    float raw[2][4][8];
#pragma unroll
    for (int ni = 0; ni < 2; ++ni) {
      const int nt = nts[ni];
#pragma unroll
      for (int kt = 0; kt < 4; ++kt)
        if (kt <= (nt >> 1)) {
          const float* p = Bf + (nt * 16 + lr) * 128 + kt * 32 + q * 8;
          *(float4*)&raw[ni][kt][0] = *(const float4*)p;
          *(float4*)&raw[ni][kt][4] = *(const float4*)(p + 4);
        }
    }
#pragma unroll
    for (int ni = 0; ni < 2; ++ni) {
      const int nt = nts[ni];
#pragma unroll
      for (int kt = 0; kt < 4; ++kt)
        if (kt <= (nt >> 1)) split8(raw[ni][kt], bh[ni][kt], bl[ni][kt]);
    }
  } else {
#pragma unroll
    for (int ni = 0; ni < 2; ++ni) {
      const int nt = nts[ni];
#pragma unroll
      for (int kt = 0; kt < 4; ++kt)
        if (kt <= (nt >> 1)) {
          const int o = (nt * 16 + lr) * 128 + kt * 32 + q * 8;
          bh[ni][kt] = *(const f16x8*)(Bh16 + o);
          bl[ni][kt] = *(const f16x8*)(Bl16 + o);
        }
    }
  }
  f32x4 acc[2][2];
#pragma unroll
  for (int bt = 0; bt < 2; ++bt)
#pragma unroll
    for (int ni = 0; ni < 2; ++ni) acc[bt][ni] = (f32x4){0.f, 0.f, 0.f, 0.f};
#pragma unroll
  for (int ni = 0; ni < 2; ++ni) {
    const int nt = nts[ni];
#pragma unroll
    for (int kt = 0; kt < 4; ++kt)
      if (kt <= (nt >> 1)) {
        acc[0][ni] = mfma3(ah[0][kt], al[0][kt], bh[ni][kt], bl[ni][kt], acc[0][ni]);
        acc[1][ni] = mfma3(ah[1][kt], al[1][kt], bh[ni][kt], bl[ni][kt], acc[1][ni]);
      }
  }
  __syncthreads();
#pragma unroll
  for (int bt = 0; bt < 2; ++bt)
#pragma unroll
    for (int ni = 0; ni < 2; ++ni) {
      const int nt = nts[ni];
      float v[4] = {acc[bt][ni][0], acc[bt][ni][1], acc[bt][ni][2], acc[bt][ni][3]};
      const int b0 = bt * 16 + q * 4;
      if (EXTRA == 2) {
        const float4 w4 = *(const float4*)(aux0 + (nt * 16 + lr) * 32 + b0);
        v[0] += w4.x; v[1] += w4.y; v[2] += w4.z; v[3] += w4.w;
      } else if (EXTRA == 1) {
        const float4 x4 = *(const float4*)(aux0 + b0);
        const float bn = aux1[nt * 16 + lr];
        v[0] += bn * x4.x; v[1] += bn * x4.y; v[2] += bn * x4.z; v[3] += bn * x4.w;
      }
      if (outp) {
#pragma unroll
        for (int r = 0; r < 4; ++r) outp[(b0 + r) * 128 + nt * 16 + lr] = v[r];
      }
#pragma unroll
      for (int r = 0; r < 4; ++r) {
        const int o = (b0 + r) * LDK + nt * 16 + lr;
        const f16 hh = (f16)v[r];
        Sh[o] = hh;
        Sl[o] = (f16)(v[r] - (float)hh);
      }
    }
  __syncthreads();
}

// ---------------------------------------------------------------------------
// K1: chunk units. grid 512 (c = bid>>1, h = bid&1), 320 threads.
__global__ __launch_bounds__(320) void k1_chunks(const float* __restrict__ A,
                                                 const float* __restrict__ x,
                                                 const float* __restrict__ Bv,
                                                 f16* __restrict__ Mh,
                                                 f16* __restrict__ Ml,
                                                 float* __restrict__ Wf) {
  __shared__ f16 Ph[80 * LDK], Pl[80 * LDK];
  const int tid = threadIdx.x;
  const int c = blockIdx.x >> 1, h = blockIdx.x & 1;
  const int l0 = 4 * c;
  const float* A0 = A + (size_t)l0 * 16384;
  for (int t = tid; t < 2048; t += 320) {
    const int k = t >> 4, u = t & 15;
    const int slot = u >> 2, fo = (u & 3) * 4;
    const int mtg = slot2mt(h, slot);
    const float4 v = *(const float4*)(A0 + k * 128 + mtg * 16 + fo);
    const float vv[4] = {v.x, v.y, v.z, v.w};
#pragma unroll
    for (int e = 0; e < 4; ++e) {
      const f16 hh = (f16)vv[e];
      Ph[(slot * 16 + fo + e) * LDK + k] = hh;
      Pl[(slot * 16 + fo + e) * LDK + k] = (f16)(vv[e] - (float)hh);
    }
  }
  for (int t = tid; t < 512; t += 320) {
    const int b = t >> 5, n4 = (t & 31) * 4;
    const float xb = x[l0 * 32 + h * 16 + b];
#pragma unroll
    for (int e = 0; e < 4; ++e) {
      const float u = xb * Bv[l0 * 128 + n4 + e];
      const f16 hh = (f16)u;
      Ph[(64 + b) * LDK + n4 + e] = hh;
      Pl[(64 + b) * LDK + n4 + e] = (f16)(u - (float)hh);
    }
  }
  __syncthreads();
  const int wv = tid >> 6;
  const int mt = (wv == 4) ? (8 + h) : slot2mt(h, wv);
#pragma unroll 1
  for (int j = 1; j <= 3; ++j) {
    const int l = l0 + j;
    chain_step<true, 1>(A + (size_t)l * 16384, nullptr, nullptr, x + l * 32,
                        Bv + l * 128, Ph, Pl, wv, mt);
  }
  chain_copyout(Ph, Pl, h, Mh + (size_t)c * 16384, Ml + (size_t)c * 16384,
                Wf + (size_t)c * 4096);
}

// ---------------------------------------------------------------------------
// Kogge-Stone level D over within-group (16) prefixes. grid 512, 320 thr.
// out[node] = (j >= D) ? in[node] o in[node-D] : in[node].
template <int D>
__global__ __launch_bounds__(320) void ks_level(const f16* __restrict__ iMh,
                                                const f16* __restrict__ iMl,
                                                const float* __restrict__ iW,
                                                f16* __restrict__ oMh,
                                                f16* __restrict__ oMl,
                                                float* __restrict__ oW) {
  __shared__ f16 Ph[80 * LDK], Pl[80 * LDK];
  const int tid = threadIdx.x;
  const int node = blockIdx.x >> 1, h = blockIdx.x & 1;
  const int j = node & 15;
  if (j < D) {  // passthrough copy (this half)
    const size_t mo = (size_t)node * 16384 + h * 8192;
    for (int t = tid; t < 1024; t += 320) {
      *(f16x8*)(oMh + mo + t * 8) = *(const f16x8*)(iMh + mo + t * 8);
      *(f16x8*)(oMl + mo + t * 8) = *(const f16x8*)(iMl + mo + t * 8);
    }
    const size_t wo = (size_t)node * 4096 + h * 2048;
    for (int t = tid; t < 512; t += 320)
      *(float4*)(oW + wo + t * 4) = *(const float4*)(iW + wo + t * 4);
    return;
  }
  const int prev = node - D;
  // init P' = M_prev^T | w_prev^T
  const f16* pMh = iMh + (size_t)prev * 16384;
  const f16* pMl = iMl + (size_t)prev * 16384;
  for (int t = tid; t < 1024; t += 320) {
    const int k = t >> 3, u = t & 7;
    const int slot = u >> 1, half = u & 1;
    const int mtg = slot2mt(h, slot);
    const f16x8 hv = *(const f16x8*)(pMh + k * 128 + mtg * 16 + half * 8);
    const f16x8 lv = *(const f16x8*)(pMl + k * 128 + mtg * 16 + half * 8);
#pragma unroll
    for (int e = 0; e < 8; ++e) {
      Ph[(slot * 16 + half * 8 + e) * LDK + k] = hv[e];
      Pl[(slot * 16 + half * 8 + e) * LDK + k] = lv[e];
    }
  }
  const float* pW = iW + (size_t)prev * 4096;
  for (int t = tid; t < 2048; t += 320) {
    const int n = t >> 4, b = t & 15;
    const float wv0 = pW[n * 32 + h * 16 + b];
    const f16 hh = (f16)wv0;
    Ph[(64 + b) * LDK + n] = hh;
    Pl[(64 + b) * LDK + n] = (f16)(wv0 - (float)hh);
  }
  __syncthreads();
  const int wv = tid >> 6;
  const int mt = (wv == 4) ? (8 + h) : slot2mt(h, wv);
  chain_step<false, 2>(nullptr, iMh + (size_t)node * 16384,
                       iMl + (size_t)node * 16384, iW + (size_t)node * 4096,
                       nullptr, Ph, Pl, wv, mt);
  chain_copyout(Ph, Pl, h, oMh + (size_t)node * 16384,
                oMl + (size_t)node * 16384, oW + (size_t)node * 4096);
}

// ---------------------------------------------------------------------------
// kgroup: entry states E[g] from group totals (node 16g+15). grid 16, 256 thr.
__global__ __launch_bounds__(256) void kgroup(const f16* __restrict__ Mh,
                                              const f16* __restrict__ Ml,
                                              const float* __restrict__ Wf,
                                              f16* __restrict__ Eh,
                                              f16* __restrict__ El) {
  __shared__ f16 Sh[32 * LDK], Sl[32 * LDK];
  const int tid = threadIdx.x;
  const int g = blockIdx.x;
  for (int t = tid; t < 32 * LDK; t += 256) { Sh[t] = (f16)0.f; Sl[t] = (f16)0.f; }
  __syncthreads();
#pragma unroll 1
  for (int hh = 0; hh < g; ++hh) {
    const int nd = 16 * hh + 15;
    state_step<false, 2>(nullptr, Mh + (size_t)nd * 16384, Ml + (size_t)nd * 16384,
                         Wf + (size_t)nd * 4096, nullptr, Sh, Sl, nullptr);
  }
  for (int t = tid; t < 512; t += 256) {
    const int b = t >> 4, k8 = (t & 15) * 8;
    *(f16x8*)(Eh + (size_t)g * 4096 + b * 128 + k8) = *(const f16x8*)(Sh + b * LDK + k8);
    *(f16x8*)(El + (size_t)g * 4096 + b * 128 + k8) = *(const f16x8*)(Sl + b * LDK + k8);
  }
}

// ---------------------------------------------------------------------------
// K3: replay. grid 256, 256 thr. entry = E[g]; if j>0 apply prefix node c-1.
__global__ __launch_bounds__(256) void k3_replay(const float* __restrict__ A,
                                                 const float* __restrict__ x,
                                                 const float* __restrict__ Bv,
                                                 const f16* __restrict__ Mh,
                                                 const f16* __restrict__ Ml,
                                                 const float* __restrict__ Wf,
                                                 const f16* __restrict__ Eh,
                                                 const f16* __restrict__ El,
                                                 float* __restrict__ out) {
  __shared__ f16 Sh[32 * LDK], Sl[32 * LDK];
  const int tid = threadIdx.x;
  const int c = blockIdx.x, g = c >> 4, j = c & 15;
  for (int t = tid; t < 512; t += 256) {
    const int b = t >> 4, k8 = (t & 15) * 8;
    *(f16x8*)(Sh + b * LDK + k8) = *(const f16x8*)(Eh + (size_t)g * 4096 + b * 128 + k8);
    *(f16x8*)(Sl + b * LDK + k8) = *(const f16x8*)(El + (size_t)g * 4096 + b * 128 + k8);
  }
  __syncthreads();
  if (j > 0) {
    const int nd = c - 1;  // within-group inclusive prefix through chunk c-1
    state_step<false, 2>(nullptr, Mh + (size_t)nd * 16384, Ml + (size_t)nd * 16384,
                         Wf + (size_t)nd * 4096, nullptr, Sh, Sl, nullptr);
  }
#pragma unroll 1
  for (int t4 = 0; t4 < 4; ++t4) {
    const int l = 4 * c + t4;
    state_step<true, 1>(A + (size_t)l * 16384, nullptr, nullptr, x + l * 32,
                        Bv + l * 128, Sh, Sl, out + (size_t)l * 4096);
  }
}

// ---------------------------------------------------------------------------
extern "C" void kernel_launch(void* const* d_in, const int* in_sizes, int n_in,
                              void* d_out, int out_size, void* d_ws, size_t ws_size,
                              hipStream_t stream) {
  const float* x  = (const float*)d_in[0];  // (1024, 32)
  const float* A  = (const float*)d_in[1];  // (1024, 128, 128) lower-triangular
  const float* Bv = (const float*)d_in[2];  // (1024, 128)
  float* out = (float*)d_out;               // (1024, 32, 128)

  // buffer A
  f16* MhA = (f16*)d_ws;                    // 256*16384 f16
  f16* MlA = MhA + 256 * 16384;
  float* WA = (float*)(MlA + 256 * 16384);  // 256*4096 f32
  // buffer B
  f16* MhB = (f16*)(WA + 256 * 4096);
  f16* MlB = MhB + 256 * 16384;
  float* WB = (float*)(MlB + 256 * 16384);
  // entry states
  f16* Eh = (f16*)(WB + 256 * 4096);        // 16*4096
  f16* El = Eh + 16 * 4096;                 // total ~42.2 MB

  k1_chunks<<<512, 320, 0, stream>>>(A, x, Bv, MhA, MlA, WA);
  ks_level<1><<<512, 320, 0, stream>>>(MhA, MlA, WA, MhB, MlB, WB);
  ks_level<2><<<512, 320, 0, stream>>>(MhB, MlB, WB, MhA, MlA, WA);
  ks_level<4><<<512, 320, 0, stream>>>(MhA, MlA, WA, MhB, MlB, WB);
  ks_level<8><<<512, 320, 0, stream>>>(MhB, MlB, WB, MhA, MlA, WA);
  kgroup<<<16, 256, 0, stream>>>(MhA, MlA, WA, Eh, El);
  k3_replay<<<256, 256, 0, stream>>>(A, x, Bv, MhA, MlA, WA, Eh, El, out);
}